// Round 3
// baseline (339.886 us; speedup 1.0000x reference)
//
#include <hip/hip_runtime.h>
#include <hip/hip_bf16.h>
#include <math.h>

constexpr int kBS = 2;
constexpr int kNQ = 20197;
constexpr int kNV = 20197;
constexpr int kM  = kBS * kNQ;   // 40394
constexpr int kMpad = 40448;     // 316*128, slack rows for global_load_lds A-tiles

__constant__ int cLH[4] = {100, 50, 25, 13};
__constant__ int cLW[4] = {152, 76, 38, 19};
__constant__ int cLS[4] = {0, 15200, 19000, 19950};

typedef __bf16 bf16x8 __attribute__((ext_vector_type(8)));
typedef float  f32x4  __attribute__((ext_vector_type(4)));

__device__ __forceinline__ unsigned short f2bf(float x) {
    unsigned u = __float_as_uint(x);
    return (unsigned short)((u + 0x7fffu + ((u >> 16) & 1u)) >> 16);
}
__device__ __forceinline__ unsigned pack2(float a, float b) {
    return (unsigned)f2bf(a) | ((unsigned)f2bf(b) << 16);
}
__device__ __forceinline__ float bflo(unsigned u) { return __uint_as_float(u << 16); }
__device__ __forceinline__ float bfhi(unsigned u) { return __uint_as_float(u & 0xffff0000u); }
__device__ __forceinline__ void gload_lds16(const void* g, void* s) {
    __builtin_amdgcn_global_load_lds(
        (const __attribute__((address_space(1))) void*)g,
        (__attribute__((address_space(3))) void*)s, 16, 0, 0);
}

// ---------------------------------------------------------------------------
// prep: all weight transposes (fp32 KxN -> bf16 NxK) + fused bias, 1 launch.
// ---------------------------------------------------------------------------
__global__ __launch_bounds__(256) void prep(
    const float* __restrict__ Wv, const float* __restrict__ Wso,
    const float* __restrict__ Waw, const float* __restrict__ Wo,
    const float* __restrict__ bso, const float* __restrict__ baw,
    unsigned short* __restrict__ WvT, unsigned short* __restrict__ WsoawT,
    unsigned short* __restrict__ WoT, float* __restrict__ bias384)
{
    int i = blockIdx.x * 256 + threadIdx.x;
    if (i < 65536) { int n = i >> 8, k = i & 255; WvT[i] = f2bf(Wv[k * 256 + n]); return; }
    i -= 65536;
    if (i < 98304) {
        int n = i >> 8, k = i & 255;
        WsoawT[i] = f2bf(n < 256 ? Wso[k * 256 + n] : Waw[k * 128 + (n - 256)]);
        return;
    }
    i -= 98304;
    if (i < 65536) { int n = i >> 8, k = i & 255; WoT[i] = f2bf(Wo[k * 256 + n]); return; }
    i -= 65536;
    if (i < 384) bias384[i] = (i < 256) ? bso[i] : baw[i - 256];
}

// ---------------------------------------------------------------------------
// Dual fp32-A MFMA GEMM (one dispatch, two GEMMs to amortize the tail):
//   bx<2 : C0[M,256] = A0 @ BT0^T + bias0   (value -> v_b, bf16 out)
//   bx>=2: C1[M,384] = A1 @ BT1^T + bias1   (query -> soaw, bf16 out)
// 128x128 tile, 256 thr (2x2 waves), BK=32, mfma 16x16x32.
// ---------------------------------------------------------------------------
__global__ __launch_bounds__(256) void gemm_dual(
    const float* __restrict__ A0, const __hip_bfloat16* __restrict__ BT0,
    const float* __restrict__ bias0, unsigned short* __restrict__ C0,
    const float* __restrict__ A1, const __hip_bfloat16* __restrict__ BT1,
    const float* __restrict__ bias1, unsigned short* __restrict__ C1)
{
    constexpr int APITCH = 40;
    __shared__ __hip_bfloat16 As[128 * APITCH];
    __shared__ __hip_bfloat16 Bs[128 * 32];

    const int bx = blockIdx.x;
    const bool second = bx >= 2;
    const float* A = second ? A1 : A0;
    const __hip_bfloat16* BT = second ? BT1 : BT0;
    const float* bias = second ? bias1 : bias0;
    unsigned short* C = second ? C1 : C0;
    const int N = second ? 384 : 256;
    const int n0 = (second ? bx - 2 : bx) * 128;
    const int m0 = blockIdx.y * 128;

    const int t = threadIdx.x;
    const int wave = t >> 6, lane = t & 63;
    const int quad = lane >> 4, l16 = lane & 15;
    const int mw = (wave & 1) * 64, nw = (wave >> 1) * 64;
    const int sm = t >> 1;
    const int sh = (t & 1) * 16;

    f32x4 acc[4][4] = {};

    for (int k0 = 0; k0 < 256; k0 += 32) {
        __syncthreads();
        {   // stage B via global_load_lds (bf16 BT rows are k-contiguous)
            const char* bt = (const char*)BT;
            #pragma unroll
            for (int j = 0; j < 2; ++j) {
                int off = j * 4096 + t * 16;
                int row = off >> 6, kb = off & 63;
                gload_lds16(bt + (size_t)(n0 + row) * 512 + k0 * 2 + kb,
                            (char*)Bs + off);
            }
        }
        {   // stage A: fp32 load + convert
            float4 f0 = make_float4(0.f, 0.f, 0.f, 0.f), f1 = f0, f2 = f0, f3 = f0;
            if (m0 + sm < kM) {
                const float4* p = (const float4*)(A + (size_t)(m0 + sm) * 256 + k0 + sh);
                f0 = p[0]; f1 = p[1]; f2 = p[2]; f3 = p[3];
            }
            uint4 q0 = make_uint4(pack2(f0.x, f0.y), pack2(f0.z, f0.w),
                                  pack2(f1.x, f1.y), pack2(f1.z, f1.w));
            uint4 q1 = make_uint4(pack2(f2.x, f2.y), pack2(f2.z, f2.w),
                                  pack2(f3.x, f3.y), pack2(f3.z, f3.w));
            uint4* dst = (uint4*)(void*)&As[sm * APITCH + sh];
            dst[0] = q0; dst[1] = q1;
        }
        __syncthreads();
        bf16x8 afr[4], bfr[4];
        #pragma unroll
        for (int mt = 0; mt < 4; ++mt)
            afr[mt] = *(const bf16x8*)(const void*)&As[(mw + mt * 16 + l16) * APITCH + quad * 8];
        #pragma unroll
        for (int nt = 0; nt < 4; ++nt)
            bfr[nt] = *(const bf16x8*)(const void*)&Bs[(nw + nt * 16 + l16) * 32 + quad * 8];
        #pragma unroll
        for (int mt = 0; mt < 4; ++mt)
            #pragma unroll
            for (int nt = 0; nt < 4; ++nt)
                acc[mt][nt] = __builtin_amdgcn_mfma_f32_16x16x32_bf16(
                    afr[mt], bfr[nt], acc[mt][nt], 0, 0, 0);
    }

    #pragma unroll
    for (int nt = 0; nt < 4; ++nt) {
        int col = n0 + nw + nt * 16 + l16;
        float bvv = bias[col];
        #pragma unroll
        for (int mt = 0; mt < 4; ++mt) {
            #pragma unroll
            for (int i = 0; i < 4; ++i) {
                int row = m0 + mw + mt * 16 + quad * 4 + i;
                if (row < kM)
                    C[(size_t)row * N + col] = f2bf(acc[mt][nt][i] + bvv);
            }
        }
    }
}

// ---------------------------------------------------------------------------
// Final GEMM: out[M,256] = mid_b(bf16) @ WoT^T + bo + query  (fp32 out)
// A staged via global_load_lds (requires kMpad slack rows in mid_b).
// ---------------------------------------------------------------------------
__global__ __launch_bounds__(256) void gemm_final(
    const __hip_bfloat16* __restrict__ Ab, const __hip_bfloat16* __restrict__ BT,
    const float* __restrict__ bias, const float* __restrict__ res,
    float* __restrict__ C)
{
    __shared__ __hip_bfloat16 As[128 * 32];
    __shared__ __hip_bfloat16 Bs[128 * 32];

    const int t = threadIdx.x;
    const int wave = t >> 6, lane = t & 63;
    const int quad = lane >> 4, l16 = lane & 15;
    const int mw = (wave & 1) * 64, nw = (wave >> 1) * 64;
    const int m0 = blockIdx.y * 128, n0 = blockIdx.x * 128;

    f32x4 acc[4][4] = {};

    for (int k0 = 0; k0 < 256; k0 += 32) {
        __syncthreads();
        const char* bt = (const char*)BT;
        const char* ab = (const char*)Ab;
        #pragma unroll
        for (int j = 0; j < 2; ++j) {
            int off = j * 4096 + t * 16;
            int row = off >> 6, kb = off & 63;
            gload_lds16(bt + (size_t)(n0 + row) * 512 + k0 * 2 + kb, (char*)Bs + off);
            gload_lds16(ab + (size_t)(m0 + row) * 512 + k0 * 2 + kb, (char*)As + off);
        }
        __syncthreads();
        bf16x8 afr[4], bfr[4];
        #pragma unroll
        for (int mt = 0; mt < 4; ++mt)
            afr[mt] = *(const bf16x8*)(const void*)&As[(mw + mt * 16 + l16) * 32 + quad * 8];
        #pragma unroll
        for (int nt = 0; nt < 4; ++nt)
            bfr[nt] = *(const bf16x8*)(const void*)&Bs[(nw + nt * 16 + l16) * 32 + quad * 8];
        #pragma unroll
        for (int mt = 0; mt < 4; ++mt)
            #pragma unroll
            for (int nt = 0; nt < 4; ++nt)
                acc[mt][nt] = __builtin_amdgcn_mfma_f32_16x16x32_bf16(
                    afr[mt], bfr[nt], acc[mt][nt], 0, 0, 0);
    }

    #pragma unroll
    for (int nt = 0; nt < 4; ++nt) {
        int col = n0 + nw + nt * 16 + l16;
        float bvv = bias[col];
        #pragma unroll
        for (int mt = 0; mt < 4; ++mt) {
            #pragma unroll
            for (int i = 0; i < 4; ++i) {
                int row = m0 + mw + mt * 16 + quad * 4 + i;
                if (row < kM)
                    C[(size_t)row * 256 + col] =
                        acc[mt][nt][i] + bvv + res[(size_t)row * 256 + col];
            }
        }
    }
}

// ---------------------------------------------------------------------------
// Sampler: 256 threads handle 4 queries.
// Phase 1 (2 iters): thread -> one (q,h,l,p) point: fused 16-wide softmax,
//   corner offsets + validity-folded weights -> LDS (XOR-swizzled slots).
// Phase 2: wave = one query; 8 lanes per head, 4 channels/lane (dwordx2).
// ---------------------------------------------------------------------------
__global__ __launch_bounds__(256) void msda_sample(
    const __hip_bfloat16* __restrict__ v,     // (BS*NV, 256) bf16
    const __hip_bfloat16* __restrict__ soaw,  // (M, 384) bf16: so[0:256] | logits[256:384]
    const float* __restrict__ rp,             // (M, 4, 2)
    __hip_bfloat16* __restrict__ mid)         // (Mpad, 256) bf16
{
    __shared__ int   sOff[512 * 4];
    __shared__ float sW[512 * 4];
    const int t = threadIdx.x;

    #pragma unroll
    for (int it = 0; it < 2; ++it) {
        const int idx = it * 256 + t;
        const int q = idx >> 7, r = idx & 127;
        const int h = r >> 4, lp = r & 15, l = lp >> 2;
        const int bq = blockIdx.x * 4 + q;
        const bool ok = bq < kM;

        unsigned sopk = 0; float logit = 0.f;
        float2 rr = make_float2(0.f, 0.f);
        if (ok) {
            sopk  = *(const unsigned*)(const void*)(soaw + (size_t)bq * 384 + 2 * r);
            logit = bflo((unsigned)*(const unsigned short*)(const void*)
                         (soaw + (size_t)bq * 384 + 256 + r));
            rr    = *(const float2*)(rp + (size_t)bq * 8 + l * 2);
        }
        float sx = bflo(sopk), sy = bfhi(sopk);

        // softmax across the 16 (l,p) lanes of this head (lane-aligned groups)
        float mx = logit;
        #pragma unroll
        for (int s = 8; s >= 1; s >>= 1) mx = fmaxf(mx, __shfl_xor(mx, s, 16));
        float e = __expf(logit - mx);
        float sum = e;
        #pragma unroll
        for (int s = 8; s >= 1; s >>= 1) sum += __shfl_xor(sum, s, 16);
        float w = e / sum;

        const int ww = cLW[l], hh = cLH[l];
        const float fw = (float)ww, fh = (float)hh;
        float x = rr.x * fw + sx - 0.5f;   // == (rx + so/w)*w - 0.5
        float y = rr.y * fh + sy - 0.5f;
        float xf = floorf(x), yf = floorf(y);
        int x0 = (int)xf, y0 = (int)yf;
        float wx1 = x - xf, wx0 = 1.f - wx1;
        float wy1 = y - yf, wy0 = 1.f - wy1;
        bool vx0 = (x0 >= 0) & (x0 < ww);
        bool vx1 = (x0 >= -1) & (x0 + 1 < ww);
        bool vy0 = (y0 >= 0) & (y0 < hh);
        bool vy1 = (y0 >= -1) & (y0 + 1 < hh);
        int cx0 = min(max(x0, 0), ww - 1);
        int cx1 = min(max(x0 + 1, 0), ww - 1);
        int cy0 = min(max(y0, 0), hh - 1);
        int cy1 = min(max(y0 + 1, 0), hh - 1);
        const int base = cLS[l] * 256 + h * 32;

        // slot layout: [q][point-within-head][head], head XOR-swizzled vs point
        const int slot = q * 128 + lp * 8 + (h ^ (lp & 7));
        ((int4*)sOff)[slot] = make_int4(base + (cy0 * ww + cx0) * 256,
                                        base + (cy0 * ww + cx1) * 256,
                                        base + (cy1 * ww + cx0) * 256,
                                        base + (cy1 * ww + cx1) * 256);
        ((float4*)sW)[slot] = make_float4((vx0 & vy0) ? w * wx0 * wy0 : 0.f,
                                          (vx1 & vy0) ? w * wx1 * wy0 : 0.f,
                                          (vx0 & vy1) ? w * wx0 * wy1 : 0.f,
                                          (vx1 & vy1) ? w * wx1 * wy1 : 0.f);
    }
    __syncthreads();

    // phase 2: wave q; h = (t>>3)&7; 4 channels per lane
    const int q = t >> 6, h = (t >> 3) & 7, c = (t & 7) * 4;
    const int bq = blockIdx.x * 4 + q;
    const int b = (bq >= kNQ) ? 1 : 0;
    const __hip_bfloat16* vb = v + (size_t)b * kNV * 256 + c;

    float a0 = 0.f, a1 = 0.f, a2 = 0.f, a3 = 0.f;
    #pragma unroll 4
    for (int pp = 0; pp < 16; ++pp) {
        const int slot = q * 128 + pp * 8 + (h ^ (pp & 7));
        int4   o = ((const int4*)sOff)[slot];
        float4 wv = ((const float4*)sW)[slot];
        {
            uint2 u = *(const uint2*)(const void*)(vb + o.x);
            a0 += wv.x * bflo(u.x); a1 += wv.x * bfhi(u.x);
            a2 += wv.x * bflo(u.y); a3 += wv.x * bfhi(u.y);
        }
        {
            uint2 u = *(const uint2*)(const void*)(vb + o.y);
            a0 += wv.y * bflo(u.x); a1 += wv.y * bfhi(u.x);
            a2 += wv.y * bflo(u.y); a3 += wv.y * bfhi(u.y);
        }
        {
            uint2 u = *(const uint2*)(const void*)(vb + o.z);
            a0 += wv.z * bflo(u.x); a1 += wv.z * bfhi(u.x);
            a2 += wv.z * bflo(u.y); a3 += wv.z * bfhi(u.y);
        }
        {
            uint2 u = *(const uint2*)(const void*)(vb + o.w);
            a0 += wv.w * bflo(u.x); a1 += wv.w * bfhi(u.x);
            a2 += wv.w * bflo(u.y); a3 += wv.w * bfhi(u.y);
        }
    }
    if (bq < kM) {
        uint2 pk = make_uint2(pack2(a0, a1), pack2(a2, a3));
        *(uint2*)(void*)(mid + (size_t)bq * 256 + h * 32 + c) = pk;
    }
}

// ---------------------------------------------------------------------------
extern "C" void kernel_launch(void* const* d_in, const int* in_sizes, int n_in,
                              void* d_out, int out_size, void* d_ws, size_t ws_size,
                              hipStream_t stream)
{
    const float* query = (const float*)d_in[0];
    const float* value = (const float*)d_in[1];
    const float* rp    = (const float*)d_in[2];
    const float* Wv  = (const float*)d_in[5];
    const float* bv  = (const float*)d_in[6];
    const float* Wso = (const float*)d_in[7];
    const float* bso = (const float*)d_in[8];
    const float* Waw = (const float*)d_in[9];
    const float* baw = (const float*)d_in[10];
    const float* Wo  = (const float*)d_in[11];
    const float* bo  = (const float*)d_in[12];

    // d_out overlay: v_b (kM*512 B) in first half; final GEMM rewrites all of d_out.
    __hip_bfloat16* v_b = (__hip_bfloat16*)d_out;

    // ws: soaw bf16 (kM*384) | mid_b bf16 (kMpad*256) | WvT | WsoawT | WoT | bias384
    char* ws8 = (char*)d_ws;
    __hip_bfloat16* soaw  = (__hip_bfloat16*)ws8;
    char* p = ws8 + (size_t)kM * 384 * 2;
    __hip_bfloat16* mid_b = (__hip_bfloat16*)p;  p += (size_t)kMpad * 256 * 2;
    unsigned short* WvT    = (unsigned short*)p; p += 256 * 256 * 2;
    unsigned short* WsoawT = (unsigned short*)p; p += 384 * 256 * 2;
    unsigned short* WoT    = (unsigned short*)p; p += 256 * 256 * 2;
    float* bias384         = (float*)p;

    hipLaunchKernelGGL(prep, dim3(898), dim3(256), 0, stream,
                       Wv, Wso, Waw, Wo, bso, baw, WvT, WsoawT, WoT, bias384);

    hipLaunchKernelGGL(gemm_dual, dim3(5, 316), dim3(256), 0, stream,
                       value, (const __hip_bfloat16*)WvT, bv, (unsigned short*)v_b,
                       query, (const __hip_bfloat16*)WsoawT, bias384, (unsigned short*)soaw);

    hipLaunchKernelGGL(msda_sample, dim3((kM + 3) / 4), dim3(256), 0, stream,
                       v_b, soaw, rp, mid_b);

    hipLaunchKernelGGL(gemm_final, dim3(2, 316), dim3(256), 0, stream,
                       mid_b, (const __hip_bfloat16*)WoT, bo, query, (float*)d_out);
}